// Round 2
// baseline (127.860 us; speedup 1.0000x reference)
//
#include <hip/hip_runtime.h>
#include <hip/hip_bf16.h>

// VariableSelectionNetwork fused kernel, round 2.
//
// Live computation (sel fc1/fc2 and the nvh,vho einsum are dead in the ref):
//   weights = softmax(LN(GLU(x @ sel_gate_w + b) + x))            [N,32]
//   y[n,v,o] = sigmoid(x*gw+gb)*(x*gw'+gb') + (x*sw+sb)           [N,32,256]
//   out[n,o] = sum_v weights[n,v] * LN_o(y)[.,v,.]                [N,256]
//
// R1 was latency-bound: 1 block/CU, 8 waves/CU, VALUBusy 28%.
// R2: 1 row per wave, 4-wave blocks, grid=1024 (4 blocks/CU, 16 waves/CU),
// v-loop unrolled x2 for independent reduction chains.

#define VDIM 32
#define ODIM 256
#define RPB  4           // rows per block
#define TPB  256         // threads per block (4 waves)

__device__ __forceinline__ float fast_sigmoid(float g) {
    // 1 / (1 + exp(-g)); exp overflow -> inf -> rcp -> 0, correct limit.
    return __builtin_amdgcn_rcpf(1.0f + __expf(-g));
}

__global__ void __launch_bounds__(TPB, 4) vsn_fused(
    const float* __restrict__ x,     // [N,32]
    const float* __restrict__ sgw,   // [32,64] sel_gate_w
    const float* __restrict__ sgb,   // [64]
    const float* __restrict__ slg,   // [32]
    const float* __restrict__ slb,   // [32]
    const float* __restrict__ vgw,   // [32,512] var_gate_w
    const float* __restrict__ vgb,   // [32,512]
    const float* __restrict__ vsw,   // [32,256] var_skip_w
    const float* __restrict__ vsb,   // [32,256]
    const float* __restrict__ vlg,   // [32,256] var_ln_g
    const float* __restrict__ vlb,   // [32,256]
    float* __restrict__ out)         // [N,256]
{
    __shared__ float x_s[RPB][VDIM];
    __shared__ float g_s[RPB][2 * VDIM];
    __shared__ float w_s[RPB][VDIM];

    const int tid  = threadIdx.x;
    const int row0 = blockIdx.x * RPB;

    // ---- load x rows (4*32 = 128 floats) ----
    if (tid < RPB * VDIM)
        ((float*)x_s)[tid] = x[row0 * VDIM + tid];
    __syncthreads();

    // ---- Phase A1: g = x @ sel_gate_w + sel_gate_b  (4 rows x 64 cols) ----
    {
        const int r = tid >> 6, j = tid & 63;   // 256 tasks == TPB
        float acc = sgb[j];
        #pragma unroll
        for (int v = 0; v < VDIM; ++v)
            acc = fmaf(x_s[r][v], sgw[v * 64 + j], acc);
        g_s[r][j] = acc;
    }
    __syncthreads();

    // ---- Phase A2: GLU -> +x -> LN(32) -> softmax(32) -> weights ----
    if (tid < RPB * VDIM) {
        const int r = tid >> 5, v = tid & 31;
        const float gate = g_s[r][v];
        const float val  = g_s[r][VDIM + v];
        const float y    = fast_sigmoid(gate) * val + x_s[r][v];
        float s1 = y, s2 = y * y;
        #pragma unroll
        for (int m = 1; m < 32; m <<= 1) {
            s1 += __shfl_xor(s1, m, 64);
            s2 += __shfl_xor(s2, m, 64);
        }
        const float mean = s1 * (1.0f / VDIM);
        const float var  = s2 * (1.0f / VDIM) - mean * mean;
        const float rs   = __builtin_amdgcn_rsqf(var + 1e-5f);
        const float sel  = slg[v] * ((y - mean) * rs) + slb[v];
        float mx = sel;
        #pragma unroll
        for (int m = 1; m < 32; m <<= 1)
            mx = fmaxf(mx, __shfl_xor(mx, m, 64));
        const float e = __expf(sel - mx);
        float se = e;
        #pragma unroll
        for (int m = 1; m < 32; m <<= 1)
            se += __shfl_xor(se, m, 64);
        w_s[r][v] = e * __builtin_amdgcn_rcpf(se);
    }
    __syncthreads();

    // ---- Phase B: per-variable GLU+skip -> LN(256) -> weighted sum ----
    // One row per wave; lane l owns o in [4l, 4l+3].
    const int wave = tid >> 6;        // 0..3 == row within block
    const int lane = tid & 63;
    const int o0   = lane << 2;
    const int row  = wave;

    float acc0 = 0.0f, acc1 = 0.0f, acc2 = 0.0f, acc3 = 0.0f;

    #pragma unroll 2
    for (int v = 0; v < VDIM; ++v) {
        const float4 ga  = *(const float4*)(vgw + v * 512 + o0);        // gate w
        const float4 va  = *(const float4*)(vgw + v * 512 + 256 + o0);  // value w
        const float4 gab = *(const float4*)(vgb + v * 512 + o0);        // gate b
        const float4 vab = *(const float4*)(vgb + v * 512 + 256 + o0);  // value b
        const float4 sw4 = *(const float4*)(vsw + v * 256 + o0);        // skip w
        const float4 sb4 = *(const float4*)(vsb + v * 256 + o0);        // skip b
        const float4 lg4 = *(const float4*)(vlg + v * 256 + o0);        // ln g
        const float4 lb4 = *(const float4*)(vlb + v * 256 + o0);        // ln b

        const float xv = x_s[row][v];

        const float y0 = fast_sigmoid(fmaf(xv, ga.x, gab.x)) * fmaf(xv, va.x, vab.x) + fmaf(xv, sw4.x, sb4.x);
        const float y1 = fast_sigmoid(fmaf(xv, ga.y, gab.y)) * fmaf(xv, va.y, vab.y) + fmaf(xv, sw4.y, sb4.y);
        const float y2 = fast_sigmoid(fmaf(xv, ga.z, gab.z)) * fmaf(xv, va.z, vab.z) + fmaf(xv, sw4.z, sb4.z);
        const float y3 = fast_sigmoid(fmaf(xv, ga.w, gab.w)) * fmaf(xv, va.w, vab.w) + fmaf(xv, sw4.w, sb4.w);

        float s1 = (y0 + y1) + (y2 + y3);
        float s2 = fmaf(y0, y0, fmaf(y1, y1, fmaf(y2, y2, y3 * y3)));
        #pragma unroll
        for (int m = 1; m < 64; m <<= 1) {
            s1 += __shfl_xor(s1, m, 64);
            s2 += __shfl_xor(s2, m, 64);
        }
        const float mean = s1 * (1.0f / ODIM);
        const float var  = s2 * (1.0f / ODIM) - mean * mean;
        const float rs   = __builtin_amdgcn_rsqf(var + 1e-5f);
        const float wv   = w_s[row][v];
        const float wrs  = wv * rs;   // w * rsqrt folded
        acc0 = fmaf(lg4.x, (y0 - mean) * wrs, fmaf(wv, lb4.x, acc0));
        acc1 = fmaf(lg4.y, (y1 - mean) * wrs, fmaf(wv, lb4.y, acc1));
        acc2 = fmaf(lg4.z, (y2 - mean) * wrs, fmaf(wv, lb4.z, acc2));
        acc3 = fmaf(lg4.w, (y3 - mean) * wrs, fmaf(wv, lb4.w, acc3));
    }

    float4 o4 = make_float4(acc0, acc1, acc2, acc3);
    *(float4*)(out + (size_t)(row0 + row) * ODIM + o0) = o4;
}

extern "C" void kernel_launch(void* const* d_in, const int* in_sizes, int n_in,
                              void* d_out, int out_size, void* d_ws, size_t ws_size,
                              hipStream_t stream) {
    const float* x   = (const float*)d_in[0];
    const float* sgw = (const float*)d_in[5];
    const float* sgb = (const float*)d_in[6];
    const float* slg = (const float*)d_in[7];
    const float* slb = (const float*)d_in[8];
    const float* vgw = (const float*)d_in[13];
    const float* vgb = (const float*)d_in[14];
    const float* vsw = (const float*)d_in[15];
    const float* vsb = (const float*)d_in[16];
    const float* vlg = (const float*)d_in[17];
    const float* vlb = (const float*)d_in[18];
    float* out = (float*)d_out;

    const int N = in_sizes[0] / VDIM;      // 4096 rows
    const int grid = N / RPB;              // 1024 blocks

    vsn_fused<<<grid, TPB, 0, stream>>>(x, sgw, sgb, slg, slb,
                                        vgw, vgb, vsw, vsb, vlg, vlb, out);
}

// Round 4
// 125.192 us; speedup vs baseline: 1.0213x; 1.0213x over previous
//
#include <hip/hip_runtime.h>
#include <hip/hip_bf16.h>

// VariableSelectionNetwork fused kernel, round 3 (resubmit — R3 never ran:
// GPU broker timeout, not a kernel failure).
//
// Live computation (sel fc1/fc2 and the nvh,vho einsum are dead in the ref):
//   weights = softmax(LN(GLU(x @ sel_gate_w + b) + x))            [N,32]
//   y[n,v,o] = sigmoid(x*gw+gb)*(x*gw'+gb') + (x*sw+sb)           [N,32,256]
//   out[n,o] = sum_v weights[n,v] * LN_o(y)[.,v,.]                [N,256]
//
// R2 was L2/L1-bandwidth-bound: every wave streamed the 256KB weight set
// through the vector path (~1GB total ~ 70% of L2 ceiling), VALUBusy 33%.
// R3: weights staged in LDS once per block, shared by 16 waves (wave = row).
// Double-buffered 2-variable chunks (16KB), async stage split: issue loads ->
// compute -> ds_write -> barrier. grid=256 (1 block/CU), 16 waves/CU.

#define VDIM 32
#define ODIM 256
#define RPB  16          // rows per block == waves per block
#define TPB  1024
#define CHUNK_V 2        // variables per staged chunk
#define NCHUNK  16       // VDIM / CHUNK_V

__device__ __forceinline__ float fast_sigmoid(float g) {
    // 1 / (1 + exp(-g)); exp overflow -> inf -> rcp -> 0, correct limit.
    return __builtin_amdgcn_rcpf(1.0f + __expf(-g));
}

__global__ void __launch_bounds__(TPB) vsn_fused(
    const float* __restrict__ x,     // [N,32]
    const float* __restrict__ sgw,   // [32,64] sel_gate_w
    const float* __restrict__ sgb,   // [64]
    const float* __restrict__ slg,   // [32]
    const float* __restrict__ slb,   // [32]
    const float* __restrict__ vgw,   // [32,512] var_gate_w
    const float* __restrict__ vgb,   // [32,512]
    const float* __restrict__ vsw,   // [32,256] var_skip_w
    const float* __restrict__ vsb,   // [32,256]
    const float* __restrict__ vlg,   // [32,256] var_ln_g
    const float* __restrict__ vlb,   // [32,256]
    float* __restrict__ out)         // [N,256]
{
    // Chunk layout (floats), per buffer of 4096 floats (16KB):
    //   [0,1024)    vgw rows  (2 x 512)
    //   [1024,2048) vgb rows
    //   [2048,2560) vsw rows  (2 x 256)
    //   [2560,3072) vsb rows
    //   [3072,3584) vlg rows
    //   [3584,4096) vlb rows
    __shared__ float wbuf[2][4096];          // 32KB double buffer
    __shared__ float x_s[RPB][VDIM];         // 2KB
    __shared__ float g_s[RPB][2 * VDIM];     // 4KB
    __shared__ float w_s[RPB][VDIM];         // 2KB

    const int tid  = threadIdx.x;
    const int row0 = blockIdx.x * RPB;

    // ---- per-thread staging source (loop-invariant base + per-chunk stride) ----
    const float* sbase;
    int sstr;
    if (tid < 256)      { sbase = vgw + (tid << 2);         sstr = 1024; }
    else if (tid < 512) { sbase = vgb + ((tid - 256) << 2); sstr = 1024; }
    else if (tid < 640) { sbase = vsw + ((tid - 512) << 2); sstr = 512;  }
    else if (tid < 768) { sbase = vsb + ((tid - 640) << 2); sstr = 512;  }
    else if (tid < 896) { sbase = vlg + ((tid - 768) << 2); sstr = 512;  }
    else                { sbase = vlb + ((tid - 896) << 2); sstr = 512;  }

    // ---- issue chunk-0 staging load early (hides under Phase A) ----
    const float4 st0 = *(const float4*)sbase;

    // ---- load x rows (16*32 = 512 floats) ----
    if (tid < RPB * VDIM)
        ((float*)x_s)[tid] = x[row0 * VDIM + tid];
    __syncthreads();

    // ---- Phase A1: g = x @ sel_gate_w + sel_gate_b (16 rows x 64 cols) ----
    {
        const int r = tid >> 6, j = tid & 63;   // 1024 tasks == TPB
        float acc = sgb[j];
        #pragma unroll
        for (int v = 0; v < VDIM; ++v)
            acc = fmaf(x_s[r][v], sgw[v * 64 + j], acc);
        g_s[r][j] = acc;
    }
    __syncthreads();

    // ---- write chunk 0 into buffer 0 (all threads), A2 on waves 0-7 ----
    ((float4*)wbuf[0])[tid & 1023] = st0;   // tid<1024 anyway; 1024 float4 slots

    if (tid < RPB * VDIM) {
        const int r = tid >> 5, v = tid & 31;
        const float gate = g_s[r][v];
        const float val  = g_s[r][VDIM + v];
        const float y    = fast_sigmoid(gate) * val + x_s[r][v];
        float s1 = y, s2 = y * y;
        #pragma unroll
        for (int m = 1; m < 32; m <<= 1) {
            s1 += __shfl_xor(s1, m, 64);
            s2 += __shfl_xor(s2, m, 64);
        }
        const float mean = s1 * (1.0f / VDIM);
        const float var  = s2 * (1.0f / VDIM) - mean * mean;
        const float rs   = __builtin_amdgcn_rsqf(var + 1e-5f);
        const float sel  = slg[v] * ((y - mean) * rs) + slb[v];
        float mx = sel;
        #pragma unroll
        for (int m = 1; m < 32; m <<= 1)
            mx = fmaxf(mx, __shfl_xor(mx, m, 64));
        const float e = __expf(sel - mx);
        float se = e;
        #pragma unroll
        for (int m = 1; m < 32; m <<= 1)
            se += __shfl_xor(se, m, 64);
        w_s[r][v] = e * __builtin_amdgcn_rcpf(se);
    }
    __syncthreads();

    // ---- Phase B: wave = row; lane owns o-quad [4l, 4l+3] ----
    const int wave = tid >> 6;        // 0..15 == row within block
    const int lane = tid & 63;
    const int o0   = lane << 2;

    float acc0 = 0.0f, acc1 = 0.0f, acc2 = 0.0f, acc3 = 0.0f;

    for (int c = 0; c < NCHUNK; ++c) {
        // issue next chunk's staging load (1 float4/thread) before compute
        float4 pf;
        if (c < NCHUNK - 1)
            pf = *(const float4*)(sbase + (c + 1) * sstr);

        const float* buf = wbuf[c & 1];

        #pragma unroll
        for (int v4 = 0; v4 < CHUNK_V; ++v4) {
            const int v = c * CHUNK_V + v4;
            const float4 ga  = *(const float4*)(buf + v4 * 512 + o0);
            const float4 va  = *(const float4*)(buf + v4 * 512 + 256 + o0);
            const float4 gab = *(const float4*)(buf + 1024 + v4 * 512 + o0);
            const float4 vab = *(const float4*)(buf + 1024 + v4 * 512 + 256 + o0);
            const float4 sw4 = *(const float4*)(buf + 2048 + v4 * 256 + o0);
            const float4 sb4 = *(const float4*)(buf + 2560 + v4 * 256 + o0);
            const float4 lg4 = *(const float4*)(buf + 3072 + v4 * 256 + o0);
            const float4 lb4 = *(const float4*)(buf + 3584 + v4 * 256 + o0);

            const float xv = x_s[wave][v];   // LDS broadcast

            const float y0 = fast_sigmoid(fmaf(xv, ga.x, gab.x)) * fmaf(xv, va.x, vab.x) + fmaf(xv, sw4.x, sb4.x);
            const float y1 = fast_sigmoid(fmaf(xv, ga.y, gab.y)) * fmaf(xv, va.y, vab.y) + fmaf(xv, sw4.y, sb4.y);
            const float y2 = fast_sigmoid(fmaf(xv, ga.z, gab.z)) * fmaf(xv, va.z, vab.z) + fmaf(xv, sw4.z, sb4.z);
            const float y3 = fast_sigmoid(fmaf(xv, ga.w, gab.w)) * fmaf(xv, va.w, vab.w) + fmaf(xv, sw4.w, sb4.w);

            float s1 = (y0 + y1) + (y2 + y3);
            float s2 = fmaf(y0, y0, fmaf(y1, y1, fmaf(y2, y2, y3 * y3)));
            #pragma unroll
            for (int m = 1; m < 64; m <<= 1) {
                s1 += __shfl_xor(s1, m, 64);
                s2 += __shfl_xor(s2, m, 64);
            }
            const float mean = s1 * (1.0f / ODIM);
            const float var  = s2 * (1.0f / ODIM) - mean * mean;
            const float rs   = __builtin_amdgcn_rsqf(var + 1e-5f);
            const float wv   = w_s[wave][v];
            const float wrs  = wv * rs;
            acc0 = fmaf(lg4.x, (y0 - mean) * wrs, fmaf(wv, lb4.x, acc0));
            acc1 = fmaf(lg4.y, (y1 - mean) * wrs, fmaf(wv, lb4.y, acc1));
            acc2 = fmaf(lg4.z, (y2 - mean) * wrs, fmaf(wv, lb4.z, acc2));
            acc3 = fmaf(lg4.w, (y3 - mean) * wrs, fmaf(wv, lb4.w, acc3));
        }

        // write next chunk; one barrier per chunk covers both the new writes
        // and the end-of-read of buf[c&1] (which gets overwritten at c+2).
        if (c < NCHUNK - 1)
            ((float4*)wbuf[(c + 1) & 1])[tid & 1023] = pf;
        __syncthreads();
    }

    float4 o4 = make_float4(acc0, acc1, acc2, acc3);
    *(float4*)(out + (size_t)(row0 + wave) * ODIM + o0) = o4;
}

extern "C" void kernel_launch(void* const* d_in, const int* in_sizes, int n_in,
                              void* d_out, int out_size, void* d_ws, size_t ws_size,
                              hipStream_t stream) {
    const float* x   = (const float*)d_in[0];
    const float* sgw = (const float*)d_in[5];
    const float* sgb = (const float*)d_in[6];
    const float* slg = (const float*)d_in[7];
    const float* slb = (const float*)d_in[8];
    const float* vgw = (const float*)d_in[13];
    const float* vgb = (const float*)d_in[14];
    const float* vsw = (const float*)d_in[15];
    const float* vsb = (const float*)d_in[16];
    const float* vlg = (const float*)d_in[17];
    const float* vlb = (const float*)d_in[18];
    float* out = (float*)d_out;

    const int N = in_sizes[0] / VDIM;      // 4096 rows
    const int grid = N / RPB;              // 256 blocks, 1 per CU

    vsn_fused<<<grid, TPB, 0, stream>>>(x, sgw, sgb, slg, slb,
                                        vgw, vgb, vsw, vsb, vlg, vlb, out);
}